// Round 4
// baseline (1303.543 us; speedup 1.0000x reference)
//
#include <hip/hip_runtime.h>
#include <cmath>

typedef float floatx4 __attribute__((ext_vector_type(4)));
typedef __bf16 bf16x8 __attribute__((ext_vector_type(8)));

#define NDT 512
#define NEL (512 * 512)
#define NELF 262144.0f

// ws float offsets
#define BUF_OFF 1024                 // y buffer (NEL fp32): A0 in, A_f out
#define AF0_OFF (1024 + NEL)         // A-fragments parity 0 (bf16, 1 MiB)
#define AF1_OFF (1024 + 2 * NEL)     // A-fragments parity 1
#define BF_OFF (1024 + 3 * NEL)      // packed Ct B-fragments (bf16, 1 MiB)
// ctl region ws[0..1023]: [0..31] CNT (uint), [32] GCNT (uint), [40..63] gACC,
//                         [64..831] rgACC[32][24]

#define RTOLc 1e-3f
#define ATOLc 1e-6f
#define TAc 1.0f
#define TBc 1.0f
#define TCc 0.0f

union UB { uint4 u; bf16x8 v; };

__device__ __forceinline__ uint32_t f2bf(float f) {
  uint32_t u = __float_as_uint(f);
  return (u + 0x7fffu + ((u >> 16) & 1u)) >> 16;
}

// ---------------- fp32 GEMM for A0 = x@P and out = A_f@F (runs twice, not hot) ----
__global__ __launch_bounds__(256) void gemm_k512(const float* __restrict__ A,
                                                 const float* __restrict__ Bm,
                                                 float* __restrict__ out,
                                                 float* __restrict__ zacc) {
  __shared__ float sc[16][520];
  if (zacc && blockIdx.x == 0) {
    for (int i = threadIdx.x; i < 1024; i += 256) zacc[i] = 0.0f;
  }
  int row0 = (blockIdx.x >> 3) * 16;
  int colb = (blockIdx.x & 7) * 64;
  for (int idx = threadIdx.x; idx < 16 * 512; idx += 256) {
    int r = idx >> 9, kk = idx & 511;
    sc[r][kk] = A[(size_t)(row0 + r) * NDT + kk];
  }
  __syncthreads();
  int row = threadIdx.x >> 4;
  int col0 = colb + (threadIdx.x & 15) * 4;
  float4 acc = {0.f, 0.f, 0.f, 0.f};
  const float* bp = Bm + col0;
#pragma unroll 4
  for (int kk = 0; kk < 512; kk += 4) {
    float4 sv = *(const float4*)(&sc[row][kk]);
    float4 b0 = *(const float4*)(bp + (size_t)(kk + 0) * NDT);
    float4 b1 = *(const float4*)(bp + (size_t)(kk + 1) * NDT);
    float4 b2 = *(const float4*)(bp + (size_t)(kk + 2) * NDT);
    float4 b3 = *(const float4*)(bp + (size_t)(kk + 3) * NDT);
    acc.x += sv.x * b0.x + sv.y * b1.x + sv.z * b2.x + sv.w * b3.x;
    acc.y += sv.x * b0.y + sv.y * b1.y + sv.z * b2.y + sv.w * b3.y;
    acc.z += sv.x * b0.z + sv.y * b1.z + sv.z * b2.z + sv.w * b3.z;
    acc.w += sv.x * b0.w + sv.y * b1.w + sv.z * b2.w + sv.w * b3.w;
  }
  *(float4*)(out + (size_t)(row0 + row) * NDT + col0) = acc;
}

// ---------------- pack C (fp32 [512][512][2]) -> bf16 B-fragments of Ct[K][i] ----
__global__ __launch_bounds__(256) void pack_c(const float* __restrict__ C,
                                              __bf16* __restrict__ Bf) {
  int t = blockIdx.x * 256 + threadIdx.x;  // 0..131071
  int i = t >> 8;
  int pr = t & 255;  // K0 = pr*4
  floatx4 v = *(const floatx4*)(C + (size_t)i * 1024 + pr * 4);
  uint32_t w0 = f2bf(v[0]) | (f2bf(v[1]) << 16);
  uint32_t w1 = f2bf(v[2]) | (f2bf(v[3]) << 16);
  int c0 = i >> 4;
  int kc = pr >> 3;
  int lq = (pr >> 1) & 3;
  int ln = (i & 15) | (lq << 4);
  int jp = (pr & 1) * 4;
  uint2 val; val.x = w0; val.y = w1;
  *(uint2*)(Bf + ((size_t)(c0 * 32 + kc) * 64 + ln) * 8 + jp) = val;
}

// ---------------- cooperative RK45: 256 blocks, block = 16 rows x 64 cols ----------
// rg = blockIdx&31 (row-group of 16 rows), cb = blockIdx>>5 (col slice of 64).
// Partner blocks (same rg) exchange basis A-fragments through L2/L3 per stage.
__global__ __launch_bounds__(256, 1) void ode_mfma(float* __restrict__ ws) {
  __shared__ float red[4][16][65];
  __shared__ float bred[4];
  __shared__ float shb0s, shb1s;

  unsigned* CNT = (unsigned*)ws;           // [0..31] per-rg arrival counters
  unsigned* GCNT = ((unsigned*)ws) + 32;   // global arrival counter
  float* gACC = ws + 40;                   // [24] global sums
  float* rgACC = ws + 64;                  // [32][24] per-rg partial sums
  float* bufY = ws + BUF_OFF;
  __bf16* AfA = (__bf16*)(ws + AF0_OFF);
  __bf16* AfB = (__bf16*)(ws + AF1_OFF);
  const __bf16* Bf = (const __bf16*)(ws + BF_OFF);

  const int tid = threadIdx.x;
  const int lane = tid & 63;
  const int w = tid >> 6;          // wave id = K-chunk [256w, 256w+256)
  const int cb = blockIdx.x >> 5;  // col-slice 64*cb..64*cb+63
  const int rg = blockIdx.x & 31;  // rows 16*rg..16*rg+15

  // persistent B fragments: wave w, col-frags cb*4+cf, K-lines kc = 8w..8w+7
  UB Breg[4][8];
#pragma unroll
  for (int cf = 0; cf < 4; ++cf)
#pragma unroll
    for (int i = 0; i < 8; ++i)
      Breg[cf][i].u =
          *(const uint4*)(Bf + (((size_t)(cb * 4 + cf) * 32 + 8 * w + i) * 64 + lane) * 8);

  int rg_phase = 0, g_phase = 0, par = 0;

  auto rg_barrier = [&]() {
    __threadfence();  // release this thread's basis stores
    __syncthreads();
    ++rg_phase;
    if (tid == 0) {
      __hip_atomic_fetch_add(&CNT[rg], 1u, __ATOMIC_RELEASE, __HIP_MEMORY_SCOPE_AGENT);
      while (__hip_atomic_load(&CNT[rg], __ATOMIC_ACQUIRE, __HIP_MEMORY_SCOPE_AGENT) <
             8u * (unsigned)rg_phase)
        __builtin_amdgcn_s_sleep(1);
    }
    __syncthreads();
    __threadfence();  // acquire: invalidate L1/L2 so partner basis reads are fresh
  };

  // thread owns rows 4w+r (r=0..3) of its rg, col = lane of its slice
  const int kcg = 4 * cb + (lane >> 4);
  const int albase = ((lane >> 2) & 3) << 4;
  const int jboff = (lane & 3) * 4;

  auto write_basis = [&](floatx4 av, float targ) {
    char* lineb = (char*)(par ? AfB : AfA) + ((size_t)(rg * 32 + kcg) * 64) * 16 + jboff;
#pragma unroll
    for (int r = 0; r < 4; ++r) {
      float s, c;
      __sincosf(TAc * av[r] + targ, &s, &c);
      int al = (4 * w + r) | albase;
      *(uint32_t*)(lineb + al * 16) = f2bf(s) | (f2bf(c) << 16);
    }
  };

  auto gemm = [&]() -> floatx4 {
    const char* Ab =
        (const char*)(par ? AfB : AfA) + ((size_t)(rg * 32 + 8 * w) * 64 + lane) * 16;
    UB a[8];
#pragma unroll
    for (int i = 0; i < 8; ++i) a[i].u = *(const uint4*)(Ab + (size_t)i * 1024);
    floatx4 acc0 = {0.f, 0.f, 0.f, 0.f}, acc1 = acc0, acc2 = acc0, acc3 = acc0;
#pragma unroll
    for (int i = 0; i < 8; ++i) {
      acc0 = __builtin_amdgcn_mfma_f32_16x16x32_bf16(a[i].v, Breg[0][i].v, acc0, 0, 0, 0);
      acc1 = __builtin_amdgcn_mfma_f32_16x16x32_bf16(a[i].v, Breg[1][i].v, acc1, 0, 0, 0);
      acc2 = __builtin_amdgcn_mfma_f32_16x16x32_bf16(a[i].v, Breg[2][i].v, acc2, 0, 0, 0);
      acc3 = __builtin_amdgcn_mfma_f32_16x16x32_bf16(a[i].v, Breg[3][i].v, acc3, 0, 0, 0);
    }
    __syncthreads();  // guard red reuse
    const int q = lane >> 4, l4 = lane & 15;
#pragma unroll
    for (int ri = 0; ri < 4; ++ri) {
      red[w][4 * q + ri][l4] = acc0[ri];
      red[w][4 * q + ri][16 + l4] = acc1[ri];
      red[w][4 * q + ri][32 + l4] = acc2[ri];
      red[w][4 * q + ri][48 + l4] = acc3[ri];
    }
    __syncthreads();
    floatx4 o;
#pragma unroll
    for (int r = 0; r < 4; ++r)
      o[r] = red[0][4 * w + r][lane] + red[1][4 * w + r][lane] + red[2][4 * w + r][lane] +
             red[3][4 * w + r][lane];
    par ^= 1;  // next basis write goes to the other buffer
    return o;
  };

  auto block_sum = [&](float v) -> float {
#pragma unroll
    for (int o = 32; o; o >>= 1) v += __shfl_down(v, o, 64);
    __syncthreads();
    if (lane == 0) bred[w] = v;
    __syncthreads();
    return (tid == 0) ? (bred[0] + bred[1] + bred[2] + bred[3]) : 0.0f;
  };

  auto grid_reduce = [&](float va, float vb, int sa, int sb, bool two) -> float2 {
    float ba = block_sum(va);
    float bb = two ? block_sum(vb) : 0.0f;
    ++rg_phase;
    if (tid == 0) {
      __hip_atomic_fetch_add(&rgACC[rg * 24 + sa], ba, __ATOMIC_RELAXED,
                             __HIP_MEMORY_SCOPE_AGENT);
      if (two)
        __hip_atomic_fetch_add(&rgACC[rg * 24 + sb], bb, __ATOMIC_RELAXED,
                               __HIP_MEMORY_SCOPE_AGENT);
      __hip_atomic_fetch_add(&CNT[rg], 1u, __ATOMIC_RELEASE, __HIP_MEMORY_SCOPE_AGENT);
    }
    ++g_phase;
    if (cb == 0 && tid == 0) {
      while (__hip_atomic_load(&CNT[rg], __ATOMIC_ACQUIRE, __HIP_MEMORY_SCOPE_AGENT) <
             8u * (unsigned)rg_phase)
        __builtin_amdgcn_s_sleep(1);
      float ra =
          __hip_atomic_load(&rgACC[rg * 24 + sa], __ATOMIC_ACQUIRE, __HIP_MEMORY_SCOPE_AGENT);
      __hip_atomic_fetch_add(&gACC[sa], ra, __ATOMIC_RELAXED, __HIP_MEMORY_SCOPE_AGENT);
      if (two) {
        float rb = __hip_atomic_load(&rgACC[rg * 24 + sb], __ATOMIC_ACQUIRE,
                                     __HIP_MEMORY_SCOPE_AGENT);
        __hip_atomic_fetch_add(&gACC[sb], rb, __ATOMIC_RELAXED, __HIP_MEMORY_SCOPE_AGENT);
      }
      __hip_atomic_fetch_add(GCNT, 1u, __ATOMIC_RELEASE, __HIP_MEMORY_SCOPE_AGENT);
    }
    if (tid == 0) {
      while (__hip_atomic_load(GCNT, __ATOMIC_ACQUIRE, __HIP_MEMORY_SCOPE_AGENT) <
             32u * (unsigned)g_phase)
        __builtin_amdgcn_s_sleep(1);
      shb0s = __hip_atomic_load(&gACC[sa], __ATOMIC_ACQUIRE, __HIP_MEMORY_SCOPE_AGENT);
      shb1s =
          two ? __hip_atomic_load(&gACC[sb], __ATOMIC_ACQUIRE, __HIP_MEMORY_SCOPE_AGENT) : 0.0f;
    }
    __syncthreads();
    return make_float2(shb0s, shb1s);
  };

  floatx4 y, fy, k2, k3, k4, k5, k6, k7, yn, av;
  const int brow = rg * 16 + 4 * w;
  const int bcol = cb * 64 + lane;
#pragma unroll
  for (int r = 0; r < 4; ++r) y[r] = bufY[(size_t)(brow + r) * NDT + bcol];

  // ---- initial step selection (scipy _select_initial_step) ----
  write_basis(y, TCc + TBc * 0.0f);
  rg_barrier();
  fy = gemm();  // f0
  {
    float s0 = 0.f, s1 = 0.f;
#pragma unroll
    for (int r = 0; r < 4; ++r) {
      float sv = ATOLc + RTOLc * fabsf(y[r]);
      float a = y[r] / sv, b = fy[r] / sv;
      s0 += a * a;
      s1 += b * b;
    }
    float2 d01 = grid_reduce(s0, s1, 0, 1, true);
    const float d0 = sqrtf(d01.x / NELF);
    const float d1 = sqrtf(d01.y / NELF);
    const float h0 = (d0 < 1e-5f || d1 < 1e-5f) ? 1e-6f : 0.01f * d0 / d1;
    av = y + h0 * fy;
    write_basis(av, TCc + TBc * h0);
    rg_barrier();
    k2 = gemm();  // f1 (temp)
    float s2 = 0.f;
#pragma unroll
    for (int r = 0; r < 4; ++r) {
      float sv = ATOLc + RTOLc * fabsf(y[r]);
      float dd = (k2[r] - fy[r]) / sv;
      s2 += dd * dd;
    }
    const float d2 = sqrtf(grid_reduce(s2, 0.f, 2, 0, false).x / NELF) / h0;
    const float dmax = fmaxf(d1, d2);
    const float h1i = (dmax <= 1e-15f) ? fmaxf(1e-6f, h0 * 1e-3f) : powf(0.01f / dmax, 0.2f);
    float h = fminf(fminf(100.0f * h0, h1i), 1.0f);
    float t = 0.0f;
    bool done = false;
    int it = 0;

    const float a21 = (float)(1.0 / 5.0);
    const float a31 = (float)(3.0 / 40.0), a32 = (float)(9.0 / 40.0);
    const float a41 = (float)(44.0 / 45.0), a42 = (float)(-56.0 / 15.0), a43 = (float)(32.0 / 9.0);
    const float a51 = (float)(19372.0 / 6561.0), a52 = (float)(-25360.0 / 2187.0),
                a53 = (float)(64448.0 / 6561.0), a54 = (float)(-212.0 / 729.0);
    const float a61 = (float)(9017.0 / 3168.0), a62 = (float)(-355.0 / 33.0),
                a63 = (float)(46732.0 / 5247.0), a64 = (float)(49.0 / 176.0),
                a65 = (float)(-5103.0 / 18656.0);
    const float b1 = (float)(35.0 / 384.0), b3 = (float)(500.0 / 1113.0),
                b4 = (float)(125.0 / 192.0), b5 = (float)(-2187.0 / 6784.0),
                b6 = (float)(11.0 / 84.0);
    const float e1c = (float)(71.0 / 57600.0), e3c = (float)(-71.0 / 16695.0),
                e4c = (float)(71.0 / 1920.0), e5c = (float)(-17253.0 / 339200.0),
                e6c = (float)(22.0 / 525.0), e7c = (float)(-1.0 / 40.0);
    const float c89 = (float)(8.0 / 9.0);

    while (true) {
      const float hs = fminf(h, 1.0f - t);

      av = y + (hs * a21) * fy;
      write_basis(av, TCc + TBc * (t + 0.2f * hs));
      rg_barrier();
      k2 = gemm();

      av = y + hs * (a31 * fy + a32 * k2);
      write_basis(av, TCc + TBc * (t + 0.3f * hs));
      rg_barrier();
      k3 = gemm();

      av = y + hs * (a41 * fy + a42 * k2 + a43 * k3);
      write_basis(av, TCc + TBc * (t + 0.8f * hs));
      rg_barrier();
      k4 = gemm();

      av = y + hs * (a51 * fy + a52 * k2 + a53 * k3 + a54 * k4);
      write_basis(av, TCc + TBc * (t + c89 * hs));
      rg_barrier();
      k5 = gemm();

      av = y + hs * (a61 * fy + a62 * k2 + a63 * k3 + a64 * k4 + a65 * k5);
      write_basis(av, TCc + TBc * (t + hs));
      rg_barrier();
      k6 = gemm();

      yn = y + hs * (b1 * fy + b3 * k3 + b4 * k4 + b5 * k5 + b6 * k6);
      write_basis(yn, TCc + TBc * (t + hs));  // FSAL stage input
      rg_barrier();
      k7 = gemm();

      float es = 0.f;
#pragma unroll
      for (int r = 0; r < 4; ++r) {
        float errc = hs * (e1c * fy[r] + e3c * k3[r] + e4c * k4[r] + e5c * k5[r] + e6c * k6[r] +
                           e7c * k7[r]);
        float sv = ATOLc + RTOLc * fmaxf(fabsf(y[r]), fabsf(yn[r]));
        float dd = errc / sv;
        es += dd * dd;
      }
      const float en = sqrtf(grid_reduce(es, 0.f, 3 + it, 0, false).x / NELF);
      const bool accept = en < 1.0f;
      const float safe = fmaxf(en, 1e-10f);
      float fac = 0.9f * powf(safe, -0.2f);
      fac = accept ? fminf(10.0f, fac) : fmaxf(0.2f, fac);
      if (accept) {
        t = t + hs;
        y = yn;
        fy = k7;
      }
      h = hs * fac;
      done = done || (t >= 1.0f - 1e-7f);
      ++it;
      if (done || it >= 20) break;
    }
  }

  // store A_f for the output GEMM
#pragma unroll
  for (int r = 0; r < 4; ++r) bufY[(size_t)(brow + r) * NDT + bcol] = y[r];
}

extern "C" void kernel_launch(void* const* d_in, const int* in_sizes, int n_in,
                              void* d_out, int out_size, void* d_ws, size_t ws_size,
                              hipStream_t stream) {
  (void)in_sizes; (void)n_in; (void)out_size; (void)ws_size;
  const float* x = (const float*)d_in[0];
  const float* P = (const float*)d_in[1];
  const float* C = (const float*)d_in[2];
  const float* F = (const float*)d_in[3];
  float* out = (float*)d_out;
  float* ws = (float*)d_ws;

  // A0 = x @ P -> bufY (block 0 also zeroes the 1024-float ctl region)
  hipLaunchKernelGGL(gemm_k512, dim3(256), dim3(256), 0, stream, x, P, ws + BUF_OFF, ws);
  // pack Ct into bf16 B-fragments (once)
  hipLaunchKernelGGL(pack_c, dim3(512), dim3(256), 0, stream, C, (__bf16*)(ws + BF_OFF));
  // cooperative RK45 (col-split, register-resident B, atomic rg barriers)
  float* wsf = ws;
  void* kargs[] = {(void*)&wsf};
  hipLaunchCooperativeKernel((void*)ode_mfma, dim3(256), dim3(256), kargs, 0, stream);
  // out = A_f @ F
  hipLaunchKernelGGL(gemm_k512, dim3(256), dim3(256), 0, stream, ws + BUF_OFF, F, out,
                     (float*)nullptr);
}

// Round 5
// 889.850 us; speedup vs baseline: 1.4649x; 1.4649x over previous
//
#include <hip/hip_runtime.h>
#include <cmath>

typedef float floatx4 __attribute__((ext_vector_type(4)));
typedef __bf16 bf16x8 __attribute__((ext_vector_type(8)));

#define NDT 512
#define NEL (512 * 512)
#define NELF 262144.0f

// ws layout (float/uint offsets). All sync counters padded to own 128-B line.
#define RCNT_OFF 1024                      // uint[48*32] reduce counters, stride 32
#define PART1_OFF 4096                     // float: slot*256 + rg*8 + cb
#define PART2_OFF 16384                    // float: (slot*32 + rg)*32
#define BUF_OFF 65536                      // y buffer (NEL fp32)
#define AF0_OFF (BUF_OFF + NEL)            // basis A-frags parity 0 (bf16)
#define AF1_OFF (BUF_OFF + 2 * NEL)        // parity 1
#define BFC_OFF (BUF_OFF + 3 * NEL)        // C frags (K=1024) bf16, 1 MiB
#define BFP_OFF (BUF_OFF + 4 * NEL)        // P frags (K=512) bf16, 512 KiB
#define BFF_OFF (BUF_OFF + 4 * NEL + NEL / 2)  // F frags

#define RTOLc 1e-3f
#define ATOLc 1e-6f
#define TAc 1.0f
#define TBc 1.0f
#define TCc 0.0f

union UB { uint4 u; bf16x8 v; };

__device__ __forceinline__ uint32_t f2bf(float f) {
  uint32_t u = __float_as_uint(f);
  return (u + 0x7fffu + ((u >> 16) & 1u)) >> 16;
}

// ---- pack C (fp32 [512][512][2]) -> bf16 K=1024 B-frags; block 0 zeroes ctl ----
__global__ __launch_bounds__(256) void pack_c(const float* __restrict__ C,
                                              __bf16* __restrict__ Bf,
                                              unsigned* __restrict__ ctl) {
  if (blockIdx.x == 0) {
    for (int i = threadIdx.x; i < 4096; i += 256) ctl[i] = 0u;
  }
  int t = blockIdx.x * 256 + threadIdx.x;  // 0..131071
  int i = t >> 8;
  int pr = t & 255;  // K0 = pr*4
  floatx4 v = *(const floatx4*)(C + (size_t)i * 1024 + pr * 4);
  uint32_t w0 = f2bf(v[0]) | (f2bf(v[1]) << 16);
  uint32_t w1 = f2bf(v[2]) | (f2bf(v[3]) << 16);
  int c0 = i >> 4;
  int kc = pr >> 3;
  int lq = (pr >> 1) & 3;
  int ln = (i & 15) | (lq << 4);
  int jp = (pr & 1) * 4;
  uint2 val; val.x = w0; val.y = w1;
  *(uint2*)(Bf + ((size_t)(c0 * 32 + kc) * 64 + ln) * 8 + jp) = val;
}

// ---- pack M (fp32 [K=512][N=512] row-major) -> bf16 K=512 B-frags ----
__global__ __launch_bounds__(256) void pack_b512(const float* __restrict__ M,
                                                 unsigned short* __restrict__ Bf) {
  int t = blockIdx.x * 256 + threadIdx.x;  // 0..65535
  int idx = t * 4;
  int k = idx >> 9;
  int n0 = idx & 511;
  floatx4 v = *(const floatx4*)(M + (size_t)k * NDT + n0);
  int kc = k >> 5;
  int lq = (k >> 3) & 3;
  int j = k & 7;
#pragma unroll
  for (int i = 0; i < 4; ++i) {
    int n = n0 + i;
    int nf = n >> 4;
    int lane = (n & 15) | (lq << 4);
    Bf[((size_t)(nf * 16 + kc) * 64 + lane) * 8 + j] = (unsigned short)f2bf(v[i]);
  }
}

// ---- MFMA GEMM: out[512x512] = A(fp32) @ B(bf16 K=512 frags); 32 blocks x 512 thr ----
__global__ __launch_bounds__(512) void gemm_mf(const float* __restrict__ A,
                                               const __bf16* __restrict__ Bf,
                                               float* __restrict__ out) {
  __shared__ __align__(16) unsigned short ldsA[16 * 64 * 8];  // 16 KiB
  const int tid = threadIdx.x, lane = tid & 63, w = tid >> 6;
  const int row0 = blockIdx.x * 16;
  for (int idx = tid; idx < 8192; idx += 512) {
    int r = idx >> 9, k = idx & 511;
    float v = A[(size_t)(row0 + r) * NDT + k];
    int al = r | (((k >> 3) & 3) << 4);
    ldsA[((size_t)(k >> 5) * 64 + al) * 8 + (k & 7)] = (unsigned short)f2bf(v);
  }
  __syncthreads();
  floatx4 acc0 = {0.f, 0.f, 0.f, 0.f}, acc1 = acc0, acc2 = acc0, acc3 = acc0;
  const __bf16* Bl = Bf + (size_t)lane * 8;
#pragma unroll
  for (int kc = 0; kc < 16; ++kc) {
    UB a;
    a.u = *(const uint4*)(ldsA + ((size_t)kc * 64 + lane) * 8);
    UB b0, b1, b2, b3;
    b0.u = *(const uint4*)(Bl + ((size_t)((4 * w + 0) * 16 + kc) * 64) * 8);
    b1.u = *(const uint4*)(Bl + ((size_t)((4 * w + 1) * 16 + kc) * 64) * 8);
    b2.u = *(const uint4*)(Bl + ((size_t)((4 * w + 2) * 16 + kc) * 64) * 8);
    b3.u = *(const uint4*)(Bl + ((size_t)((4 * w + 3) * 16 + kc) * 64) * 8);
    acc0 = __builtin_amdgcn_mfma_f32_16x16x32_bf16(a.v, b0.v, acc0, 0, 0, 0);
    acc1 = __builtin_amdgcn_mfma_f32_16x16x32_bf16(a.v, b1.v, acc1, 0, 0, 0);
    acc2 = __builtin_amdgcn_mfma_f32_16x16x32_bf16(a.v, b2.v, acc2, 0, 0, 0);
    acc3 = __builtin_amdgcn_mfma_f32_16x16x32_bf16(a.v, b3.v, acc3, 0, 0, 0);
  }
  const int q = lane >> 4, cn = lane & 15;
#pragma unroll
  for (int ri = 0; ri < 4; ++ri) {
    size_t rb = (size_t)(row0 + 4 * q + ri) * NDT + 64 * w + cn;
    out[rb] = acc0[ri];
    out[rb + 16] = acc1[ri];
    out[rb + 32] = acc2[ri];
    out[rb + 48] = acc3[ri];
  }
}

// ---- cooperative RK45: 256 blocks x 256 thr; block = 16 rows x 64 cols ----
__global__ __launch_bounds__(256, 1) void ode_mfma(float* __restrict__ ws) {
  __shared__ float red[4][16][65];
  __shared__ float bred[4];
  __shared__ float shb0s, shb1s;

  unsigned* CNT = (unsigned*)ws;                // per-rg counters, stride 32 (128 B)
  unsigned* RCNT = ((unsigned*)ws) + RCNT_OFF;  // per-slot counters, stride 32
  float* PART1 = ws + PART1_OFF;
  float* PART2 = ws + PART2_OFF;
  float* bufY = ws + BUF_OFF;
  __bf16* AfA = (__bf16*)(ws + AF0_OFF);
  __bf16* AfB = (__bf16*)(ws + AF1_OFF);
  const __bf16* Bf = (const __bf16*)(ws + BFC_OFF);

  const int tid = threadIdx.x;
  const int lane = tid & 63;
  const int w = tid >> 6;          // wave id = K-chunk
  const int cb = blockIdx.x >> 5;  // col-slice 64*cb..64*cb+63
  const int rg = blockIdx.x & 31;  // rows 16*rg..16*rg+15

  // persistent B fragments (register-resident): wave w, col-frags cb*4+cf, kc=8w+i
  UB Breg[4][8];
#pragma unroll
  for (int cf = 0; cf < 4; ++cf)
#pragma unroll
    for (int i = 0; i < 8; ++i)
      Breg[cf][i].u =
          *(const uint4*)(Bf + (((size_t)(cb * 4 + cf) * 32 + 8 * w + i) * 64 + lane) * 8);

  int rg_phase = 0, par = 0;

  auto rg_barrier = [&]() {
    __threadfence();  // release basis stores (all threads)
    __syncthreads();
    ++rg_phase;
    if (tid == 0) {
      __hip_atomic_fetch_add(&CNT[rg * 32], 1u, __ATOMIC_RELEASE, __HIP_MEMORY_SCOPE_AGENT);
      while (__hip_atomic_load(&CNT[rg * 32], __ATOMIC_ACQUIRE, __HIP_MEMORY_SCOPE_AGENT) <
             8u * (unsigned)rg_phase)
        __builtin_amdgcn_s_sleep(1);
    }
    __syncthreads();
  };

  const int kcg = 4 * cb + (lane >> 4);
  const int albase = ((lane >> 2) & 3) << 4;
  const int jboff = (lane & 3) * 4;

  auto write_basis = [&](floatx4 av, float targ) {
    char* lineb = (char*)(par ? AfB : AfA) + ((size_t)(rg * 32 + kcg) * 64) * 16 + jboff;
#pragma unroll
    for (int r = 0; r < 4; ++r) {
      float s, c;
      __sincosf(TAc * av[r] + targ, &s, &c);
      int al = (4 * w + r) | albase;
      *(uint32_t*)(lineb + al * 16) = f2bf(s) | (f2bf(c) << 16);
    }
  };

  auto gemm = [&]() -> floatx4 {
    const char* Ab =
        (const char*)(par ? AfB : AfA) + ((size_t)(rg * 32 + 8 * w) * 64 + lane) * 16;
    UB a[8];
#pragma unroll
    for (int i = 0; i < 8; ++i) a[i].u = *(const uint4*)(Ab + (size_t)i * 1024);
    floatx4 acc0 = {0.f, 0.f, 0.f, 0.f}, acc1 = acc0, acc2 = acc0, acc3 = acc0;
#pragma unroll
    for (int i = 0; i < 8; ++i) {
      acc0 = __builtin_amdgcn_mfma_f32_16x16x32_bf16(a[i].v, Breg[0][i].v, acc0, 0, 0, 0);
      acc1 = __builtin_amdgcn_mfma_f32_16x16x32_bf16(a[i].v, Breg[1][i].v, acc1, 0, 0, 0);
      acc2 = __builtin_amdgcn_mfma_f32_16x16x32_bf16(a[i].v, Breg[2][i].v, acc2, 0, 0, 0);
      acc3 = __builtin_amdgcn_mfma_f32_16x16x32_bf16(a[i].v, Breg[3][i].v, acc3, 0, 0, 0);
    }
    __syncthreads();
    const int q = lane >> 4, l4 = lane & 15;
#pragma unroll
    for (int ri = 0; ri < 4; ++ri) {
      red[w][4 * q + ri][l4] = acc0[ri];
      red[w][4 * q + ri][16 + l4] = acc1[ri];
      red[w][4 * q + ri][32 + l4] = acc2[ri];
      red[w][4 * q + ri][48 + l4] = acc3[ri];
    }
    __syncthreads();
    floatx4 o;
#pragma unroll
    for (int r = 0; r < 4; ++r)
      o[r] = red[0][4 * w + r][lane] + red[1][4 * w + r][lane] + red[2][4 * w + r][lane] +
             red[3][4 * w + r][lane];
    par ^= 1;
    return o;
  };

  auto block_sum = [&](float v) -> float {
#pragma unroll
    for (int o = 32; o; o >>= 1) v += __shfl_down(v, o, 64);
    __syncthreads();
    if (lane == 0) bred[w] = v;
    __syncthreads();
    return (tid == 0) ? (bred[0] + bred[1] + bred[2] + bred[3]) : 0.0f;
  };

  // deterministic 2-level grid reduce on padded slots
  auto grid_reduce = [&](float va, float vb, int sa, int sb, bool two) -> float2 {
    float ba = block_sum(va);
    float bb = two ? block_sum(vb) : 0.0f;
    ++rg_phase;
    if (tid == 0) {
      PART1[sa * 256 + rg * 8 + cb] = ba;
      if (two) PART1[sb * 256 + rg * 8 + cb] = bb;
      __hip_atomic_fetch_add(&CNT[rg * 32], 1u, __ATOMIC_RELEASE, __HIP_MEMORY_SCOPE_AGENT);
    }
    if (cb == 0 && tid == 0) {
      while (__hip_atomic_load(&CNT[rg * 32], __ATOMIC_ACQUIRE, __HIP_MEMORY_SCOPE_AGENT) <
             8u * (unsigned)rg_phase)
        __builtin_amdgcn_s_sleep(1);
      float ra = 0.f;
#pragma unroll
      for (int i = 0; i < 8; ++i) ra += PART1[sa * 256 + rg * 8 + i];
      PART2[(size_t)(sa * 32 + rg) * 32] = ra;
      if (two) {
        float rb = 0.f;
#pragma unroll
        for (int i = 0; i < 8; ++i) rb += PART1[sb * 256 + rg * 8 + i];
        PART2[(size_t)(sb * 32 + rg) * 32] = rb;
      }
      __hip_atomic_fetch_add(&RCNT[sa * 32], 1u, __ATOMIC_RELEASE, __HIP_MEMORY_SCOPE_AGENT);
    }
    if (tid == 0) {
      while (__hip_atomic_load(&RCNT[sa * 32], __ATOMIC_ACQUIRE, __HIP_MEMORY_SCOPE_AGENT) < 32u)
        __builtin_amdgcn_s_sleep(1);
    }
    __syncthreads();
    if (w == 0) {
      float x0 = (lane < 32) ? PART2[(size_t)(sa * 32 + lane) * 32] : 0.0f;
      float x1 = (two && lane < 32) ? PART2[(size_t)(sb * 32 + lane) * 32] : 0.0f;
#pragma unroll
      for (int o = 16; o; o >>= 1) {
        x0 += __shfl_down(x0, o, 32);
        x1 += __shfl_down(x1, o, 32);
      }
      if (lane == 0) { shb0s = x0; shb1s = x1; }
    }
    __syncthreads();
    return make_float2(shb0s, shb1s);
  };

  floatx4 y, fy, k2, k3, k4, k5, k6, k7, yn, av;
  const int brow = rg * 16 + 4 * w;
  const int bcol = cb * 64 + lane;
#pragma unroll
  for (int r = 0; r < 4; ++r) y[r] = bufY[(size_t)(brow + r) * NDT + bcol];

  // ---- initial step selection (scipy _select_initial_step) ----
  write_basis(y, TCc + TBc * 0.0f);
  rg_barrier();
  fy = gemm();  // f0
  {
    float s0 = 0.f, s1 = 0.f;
#pragma unroll
    for (int r = 0; r < 4; ++r) {
      float sv = ATOLc + RTOLc * fabsf(y[r]);
      float a = y[r] / sv, b = fy[r] / sv;
      s0 += a * a;
      s1 += b * b;
    }
    float2 d01 = grid_reduce(s0, s1, 0, 1, true);
    const float d0 = sqrtf(d01.x / NELF);
    const float d1 = sqrtf(d01.y / NELF);
    const float h0 = (d0 < 1e-5f || d1 < 1e-5f) ? 1e-6f : 0.01f * d0 / d1;
    av = y + h0 * fy;
    write_basis(av, TCc + TBc * h0);
    rg_barrier();
    k2 = gemm();  // f1 (temp)
    float s2 = 0.f;
#pragma unroll
    for (int r = 0; r < 4; ++r) {
      float sv = ATOLc + RTOLc * fabsf(y[r]);
      float dd = (k2[r] - fy[r]) / sv;
      s2 += dd * dd;
    }
    const float d2 = sqrtf(grid_reduce(s2, 0.f, 2, 0, false).x / NELF) / h0;
    const float dmax = fmaxf(d1, d2);
    const float h1i = (dmax <= 1e-15f) ? fmaxf(1e-6f, h0 * 1e-3f) : powf(0.01f / dmax, 0.2f);
    float h = fminf(fminf(100.0f * h0, h1i), 1.0f);
    float t = 0.0f;
    bool done = false;
    int it = 0;

    const float a21 = (float)(1.0 / 5.0);
    const float a31 = (float)(3.0 / 40.0), a32 = (float)(9.0 / 40.0);
    const float a41 = (float)(44.0 / 45.0), a42 = (float)(-56.0 / 15.0), a43 = (float)(32.0 / 9.0);
    const float a51 = (float)(19372.0 / 6561.0), a52 = (float)(-25360.0 / 2187.0),
                a53 = (float)(64448.0 / 6561.0), a54 = (float)(-212.0 / 729.0);
    const float a61 = (float)(9017.0 / 3168.0), a62 = (float)(-355.0 / 33.0),
                a63 = (float)(46732.0 / 5247.0), a64 = (float)(49.0 / 176.0),
                a65 = (float)(-5103.0 / 18656.0);
    const float b1 = (float)(35.0 / 384.0), b3 = (float)(500.0 / 1113.0),
                b4 = (float)(125.0 / 192.0), b5 = (float)(-2187.0 / 6784.0),
                b6 = (float)(11.0 / 84.0);
    const float e1c = (float)(71.0 / 57600.0), e3c = (float)(-71.0 / 16695.0),
                e4c = (float)(71.0 / 1920.0), e5c = (float)(-17253.0 / 339200.0),
                e6c = (float)(22.0 / 525.0), e7c = (float)(-1.0 / 40.0);
    const float c89 = (float)(8.0 / 9.0);

    while (true) {
      const float hs = fminf(h, 1.0f - t);

      av = y + (hs * a21) * fy;
      write_basis(av, TCc + TBc * (t + 0.2f * hs));
      rg_barrier();
      k2 = gemm();

      av = y + hs * (a31 * fy + a32 * k2);
      write_basis(av, TCc + TBc * (t + 0.3f * hs));
      rg_barrier();
      k3 = gemm();

      av = y + hs * (a41 * fy + a42 * k2 + a43 * k3);
      write_basis(av, TCc + TBc * (t + 0.8f * hs));
      rg_barrier();
      k4 = gemm();

      av = y + hs * (a51 * fy + a52 * k2 + a53 * k3 + a54 * k4);
      write_basis(av, TCc + TBc * (t + c89 * hs));
      rg_barrier();
      k5 = gemm();

      av = y + hs * (a61 * fy + a62 * k2 + a63 * k3 + a64 * k4 + a65 * k5);
      write_basis(av, TCc + TBc * (t + hs));
      rg_barrier();
      k6 = gemm();

      yn = y + hs * (b1 * fy + b3 * k3 + b4 * k4 + b5 * k5 + b6 * k6);
      write_basis(yn, TCc + TBc * (t + hs));  // FSAL stage input
      rg_barrier();
      k7 = gemm();

      float es = 0.f;
#pragma unroll
      for (int r = 0; r < 4; ++r) {
        float errc = hs * (e1c * fy[r] + e3c * k3[r] + e4c * k4[r] + e5c * k5[r] + e6c * k6[r] +
                           e7c * k7[r]);
        float sv = ATOLc + RTOLc * fmaxf(fabsf(y[r]), fabsf(yn[r]));
        float dd = errc / sv;
        es += dd * dd;
      }
      const float en = sqrtf(grid_reduce(es, 0.f, 3 + it, 0, false).x / NELF);
      const bool accept = en < 1.0f;
      const float safe = fmaxf(en, 1e-10f);
      float fac = 0.9f * powf(safe, -0.2f);
      fac = accept ? fminf(10.0f, fac) : fmaxf(0.2f, fac);
      if (accept) {
        t = t + hs;
        y = yn;
        fy = k7;
      }
      h = hs * fac;
      done = done || (t >= 1.0f - 1e-7f);
      ++it;
      if (done || it >= 20) break;
    }
  }

  // store A_f for the output GEMM
#pragma unroll
  for (int r = 0; r < 4; ++r) bufY[(size_t)(brow + r) * NDT + bcol] = y[r];
}

extern "C" void kernel_launch(void* const* d_in, const int* in_sizes, int n_in,
                              void* d_out, int out_size, void* d_ws, size_t ws_size,
                              hipStream_t stream) {
  (void)in_sizes; (void)n_in; (void)out_size; (void)ws_size;
  const float* x = (const float*)d_in[0];
  const float* P = (const float*)d_in[1];
  const float* C = (const float*)d_in[2];
  const float* F = (const float*)d_in[3];
  float* out = (float*)d_out;
  float* ws = (float*)d_ws;

  // pack C -> bf16 frags (block 0 zeroes the sync-counter region)
  hipLaunchKernelGGL(pack_c, dim3(512), dim3(256), 0, stream, C, (__bf16*)(ws + BFC_OFF),
                     (unsigned*)ws);
  // pack P, F -> bf16 K=512 frags
  hipLaunchKernelGGL(pack_b512, dim3(256), dim3(256), 0, stream, P,
                     (unsigned short*)(ws + BFP_OFF));
  hipLaunchKernelGGL(pack_b512, dim3(256), dim3(256), 0, stream, F,
                     (unsigned short*)(ws + BFF_OFF));
  // A0 = x @ P (bf16 MFMA) -> bufY
  hipLaunchKernelGGL(gemm_mf, dim3(32), dim3(512), 0, stream, x, (const __bf16*)(ws + BFP_OFF),
                     ws + BUF_OFF);
  // cooperative RK45 (padded-line barriers, register-resident B)
  float* wsf = ws;
  void* kargs[] = {(void*)&wsf};
  hipLaunchCooperativeKernel((void*)ode_mfma, dim3(256), dim3(256), kargs, 0, stream);
  // out = A_f @ F (bf16 MFMA)
  hipLaunchKernelGGL(gemm_mf, dim3(32), dim3(512), 0, stream, ws + BUF_OFF,
                     (const __bf16*)(ws + BFF_OFF), out);
}

// Round 6
// 182.996 us; speedup vs baseline: 7.1233x; 4.8627x over previous
//
#include <hip/hip_runtime.h>
#include <cmath>

typedef float floatx4 __attribute__((ext_vector_type(4)));
typedef __bf16 bf16x8 __attribute__((ext_vector_type(8)));

#define NDT 512
#define NEL (512 * 512)
#define NELF 262144.0f

// ws layout. uint offsets for ctl, float offsets for data.
#define RCNT_OFF 1024                      // uint[48*32] reduce counters, stride 32
#define PART1_OFF 4096                     // float: slot*256 + rg*8 + cb
#define PART2_OFF 16384                    // float: (slot*32 + rg)*32
#define BUF_OFF 65536                      // y buffer (NEL fp32)
#define AF0_OFF (BUF_OFF + NEL)            // basis A-frags parity 0 (bf16)
#define AF1_OFF (BUF_OFF + 2 * NEL)        // parity 1
#define BFC_OFF (BUF_OFF + 3 * NEL)        // C frags (K=1024) bf16, 1 MiB
#define BFP_OFF (BUF_OFF + 4 * NEL)        // P frags (K=512) bf16
#define BFF_OFF (BUF_OFF + 4 * NEL + NEL / 2)  // F frags

#define RTOLc 1e-3f
#define ATOLc 1e-6f
#define TAc 1.0f
#define TBc 1.0f
#define TCc 0.0f

union UB { uint4 u; bf16x8 v; };
union UB2 { unsigned long long q[2]; uint4 u; bf16x8 v; };

__device__ __forceinline__ uint32_t f2bf(float f) {
  uint32_t u = __float_as_uint(f);
  return (u + 0x7fffu + ((u >> 16) & 1u)) >> 16;
}

#define AST(p, v) __hip_atomic_store((p), (v), __ATOMIC_RELAXED, __HIP_MEMORY_SCOPE_AGENT)
#define ALD(p) __hip_atomic_load((p), __ATOMIC_RELAXED, __HIP_MEMORY_SCOPE_AGENT)

// ---- one-shot pack kernel: C->K1024 frags, P/F->K512 frags, zero ctl ----
__global__ __launch_bounds__(256) void pack_all(const float* __restrict__ C,
                                                const float* __restrict__ P,
                                                const float* __restrict__ F,
                                                __bf16* __restrict__ BfC,
                                                unsigned short* __restrict__ BfP,
                                                unsigned short* __restrict__ BfF,
                                                unsigned* __restrict__ ctl) {
  const int bid = blockIdx.x, tid = threadIdx.x;
  if (bid == 0) {
    for (int i = tid; i < 4096; i += 256) ctl[i] = 0u;
  }
  if (bid < 512) {
    int t = bid * 256 + tid;
    int i = t >> 8;
    int pr = t & 255;  // K0 = pr*4
    floatx4 v = *(const floatx4*)(C + (size_t)i * 1024 + pr * 4);
    uint32_t w0 = f2bf(v[0]) | (f2bf(v[1]) << 16);
    uint32_t w1 = f2bf(v[2]) | (f2bf(v[3]) << 16);
    int c0 = i >> 4;
    int kc = pr >> 3;
    int lq = (pr >> 1) & 3;
    int ln = (i & 15) | (lq << 4);
    int jp = (pr & 1) * 4;
    uint2 val; val.x = w0; val.y = w1;
    *(uint2*)(BfC + ((size_t)(c0 * 32 + kc) * 64 + ln) * 8 + jp) = val;
  } else {
    const float* M = (bid < 768) ? P : F;
    unsigned short* Bf = (bid < 768) ? BfP : BfF;
    int t = ((bid < 768) ? (bid - 512) : (bid - 768)) * 256 + tid;
    int idx = t * 4;
    int k = idx >> 9;
    int n0 = idx & 511;
    floatx4 v = *(const floatx4*)(M + (size_t)k * NDT + n0);
    int kc = k >> 5;
    int lq = (k >> 3) & 3;
    int j = k & 7;
#pragma unroll
    for (int i = 0; i < 4; ++i) {
      int n = n0 + i;
      int nf = n >> 4;
      int lane = (n & 15) | (lq << 4);
      Bf[((size_t)(nf * 16 + kc) * 64 + lane) * 8 + j] = (unsigned short)f2bf(v[i]);
    }
  }
}

// ---- MFMA GEMM: out[512x512] = A(fp32) @ B(bf16 K=512 frags); 256 blk x 256 thr ----
__global__ __launch_bounds__(256) void gemm_mf(const float* __restrict__ A,
                                               const __bf16* __restrict__ Bf,
                                               float* __restrict__ out) {
  __shared__ __align__(16) unsigned short ldsA[16 * 64 * 8];  // 16 KiB
  const int tid = threadIdx.x, lane = tid & 63, w = tid >> 6;
  const int row0 = (blockIdx.x >> 3) * 16;
  const int nf = (blockIdx.x & 7) * 4 + w;  // col-frag 0..31
  for (int idx = tid; idx < 8192; idx += 256) {
    int r = idx >> 9, k = idx & 511;
    float v = A[(size_t)(row0 + r) * NDT + k];
    int al = r | (((k >> 3) & 3) << 4);
    ldsA[((size_t)(k >> 5) * 64 + al) * 8 + (k & 7)] = (unsigned short)f2bf(v);
  }
  __syncthreads();
  floatx4 acc = {0.f, 0.f, 0.f, 0.f};
#pragma unroll
  for (int kc = 0; kc < 16; ++kc) {
    UB a, b;
    a.u = *(const uint4*)(ldsA + ((size_t)kc * 64 + lane) * 8);
    b.u = *(const uint4*)(Bf + ((size_t)(nf * 16 + kc) * 64 + lane) * 8);
    acc = __builtin_amdgcn_mfma_f32_16x16x32_bf16(a.v, b.v, acc, 0, 0, 0);
  }
  const int q = lane >> 4, cn = lane & 15;
#pragma unroll
  for (int ri = 0; ri < 4; ++ri)
    out[(size_t)(row0 + 4 * q + ri) * NDT + nf * 16 + cn] = acc[ri];
}

// ---- cooperative RK45: 256 blocks x 256 thr; block = 16 rows x 64 cols ----
// Thread owns 1 row x 4 cols. Cross-block exchange via relaxed agent-scope
// atomics (per-access coherent; no cache-wide fences, no XCD assumptions).
__global__ __launch_bounds__(256, 1) void ode_mfma(float* __restrict__ ws) {
  __shared__ __align__(16) float red[4][16][68];
  __shared__ float bred[4];
  __shared__ float shb0s, shb1s;

  unsigned* CNT = (unsigned*)ws;                // per-rg counters, stride 32
  unsigned* RCNT = ((unsigned*)ws) + RCNT_OFF;  // per-slot counters, stride 32
  float* PART1 = ws + PART1_OFF;
  float* PART2 = ws + PART2_OFF;
  float* bufY = ws + BUF_OFF;
  unsigned long long* AfA = (unsigned long long*)(ws + AF0_OFF);
  unsigned long long* AfB = (unsigned long long*)(ws + AF1_OFF);
  const __bf16* Bf = (const __bf16*)(ws + BFC_OFF);

  const int tid = threadIdx.x;
  const int lane = tid & 63;
  const int w = tid >> 6;          // wave id = K-chunk [256w,256w+256)
  const int cb = blockIdx.x >> 5;  // col-slice 64*cb..64*cb+63
  const int rg = blockIdx.x & 31;  // rows 16*rg..16*rg+15

  // persistent register-resident B fragments
  UB Breg[4][8];
#pragma unroll
  for (int cf = 0; cf < 4; ++cf)
#pragma unroll
    for (int i = 0; i < 8; ++i)
      Breg[cf][i].u =
          *(const uint4*)(Bf + (((size_t)(cb * 4 + cf) * 32 + 8 * w + i) * 64 + lane) * 8);

  int rg_phase = 0, par = 0;

  auto rg_barrier = [&]() {
    __syncthreads();  // drains vmcnt: all basis stores complete at coherence point
    ++rg_phase;
    if (tid == 0) {
      __hip_atomic_fetch_add(&CNT[rg * 32], 1u, __ATOMIC_RELAXED, __HIP_MEMORY_SCOPE_AGENT);
      while (ALD(&CNT[rg * 32]) < 8u * (unsigned)rg_phase) __builtin_amdgcn_s_sleep(1);
    }
    __syncthreads();
  };

  // thread owns row rl, global col-quad gcq
  const int rl = tid & 15;
  const int gcq = cb * 16 + (tid >> 4);
  const int kcw = gcq >> 2;
  const int alw = rl | ((gcq & 3) << 4);
  const size_t wslot = ((size_t)(rg * 32 + kcw) * 64 + alw) * 2;  // u64 units

  auto write_basis = [&](floatx4 av, float targ) {
    uint32_t d[4];
#pragma unroll
    for (int e = 0; e < 4; ++e) {
      float s, c;
      __sincosf(TAc * av[e] + targ, &s, &c);
      d[e] = f2bf(s) | (f2bf(c) << 16);
    }
    unsigned long long* Ap = (par ? AfB : AfA) + wslot;
    AST(Ap, (unsigned long long)d[0] | ((unsigned long long)d[1] << 32));
    AST(Ap + 1, (unsigned long long)d[2] | ((unsigned long long)d[3] << 32));
  };

  auto gemm = [&]() -> floatx4 {
    const unsigned long long* Ap = (par ? AfB : AfA) + ((size_t)(rg * 32 + 8 * w) * 64 + lane) * 2;
    UB2 a[8];
#pragma unroll
    for (int i = 0; i < 8; ++i) {
      a[i].q[0] = ALD(Ap + (size_t)i * 128);
      a[i].q[1] = ALD(Ap + (size_t)i * 128 + 1);
    }
    floatx4 acc0 = {0.f, 0.f, 0.f, 0.f}, acc1 = acc0, acc2 = acc0, acc3 = acc0;
#pragma unroll
    for (int i = 0; i < 8; ++i) {
      acc0 = __builtin_amdgcn_mfma_f32_16x16x32_bf16(a[i].v, Breg[0][i].v, acc0, 0, 0, 0);
      acc1 = __builtin_amdgcn_mfma_f32_16x16x32_bf16(a[i].v, Breg[1][i].v, acc1, 0, 0, 0);
      acc2 = __builtin_amdgcn_mfma_f32_16x16x32_bf16(a[i].v, Breg[2][i].v, acc2, 0, 0, 0);
      acc3 = __builtin_amdgcn_mfma_f32_16x16x32_bf16(a[i].v, Breg[3][i].v, acc3, 0, 0, 0);
    }
    __syncthreads();  // guard red reuse
    const int q = lane >> 4, l4 = lane & 15;
#pragma unroll
    for (int ri = 0; ri < 4; ++ri) {
      red[w][4 * q + ri][l4] = acc0[ri];
      red[w][4 * q + ri][16 + l4] = acc1[ri];
      red[w][4 * q + ri][32 + l4] = acc2[ri];
      red[w][4 * q + ri][48 + l4] = acc3[ri];
    }
    __syncthreads();
    const int c0 = (tid >> 4) * 4;
    floatx4 o = *(const floatx4*)&red[0][rl][c0];
    o += *(const floatx4*)&red[1][rl][c0];
    o += *(const floatx4*)&red[2][rl][c0];
    o += *(const floatx4*)&red[3][rl][c0];
    par ^= 1;
    return o;
  };

  auto block_sum = [&](float v) -> float {
#pragma unroll
    for (int o = 32; o; o >>= 1) v += __shfl_down(v, o, 64);
    __syncthreads();
    if (lane == 0) bred[w] = v;
    __syncthreads();
    return (tid == 0) ? (bred[0] + bred[1] + bred[2] + bred[3]) : 0.0f;
  };

  // deterministic 2-level grid reduce; relaxed agent atomics + explicit vmcnt order
  auto grid_reduce = [&](float va, float vb, int sa, int sb, bool two) -> float2 {
    float ba = block_sum(va);
    float bb = two ? block_sum(vb) : 0.0f;
    ++rg_phase;
    if (tid == 0) {
      AST(&PART1[sa * 256 + rg * 8 + cb], ba);
      if (two) AST(&PART1[sb * 256 + rg * 8 + cb], bb);
      asm volatile("s_waitcnt vmcnt(0)" ::: "memory");
      __hip_atomic_fetch_add(&CNT[rg * 32], 1u, __ATOMIC_RELAXED, __HIP_MEMORY_SCOPE_AGENT);
    }
    if (cb == 0 && tid == 0) {
      while (ALD(&CNT[rg * 32]) < 8u * (unsigned)rg_phase) __builtin_amdgcn_s_sleep(1);
      float ra = 0.f, rb = 0.f;
#pragma unroll
      for (int i = 0; i < 8; ++i) ra += ALD(&PART1[sa * 256 + rg * 8 + i]);
      AST(&PART2[(size_t)(sa * 32 + rg) * 32], ra);
      if (two) {
#pragma unroll
        for (int i = 0; i < 8; ++i) rb += ALD(&PART1[sb * 256 + rg * 8 + i]);
        AST(&PART2[(size_t)(sb * 32 + rg) * 32], rb);
      }
      asm volatile("s_waitcnt vmcnt(0)" ::: "memory");
      __hip_atomic_fetch_add(&RCNT[sa * 32], 1u, __ATOMIC_RELAXED, __HIP_MEMORY_SCOPE_AGENT);
    }
    if (tid == 0) {
      while (ALD(&RCNT[sa * 32]) < 32u) __builtin_amdgcn_s_sleep(1);
    }
    __syncthreads();
    if (w == 0) {
      float x0 = (lane < 32) ? ALD(&PART2[(size_t)(sa * 32 + lane) * 32]) : 0.0f;
      float x1 = (two && lane < 32) ? ALD(&PART2[(size_t)(sb * 32 + lane) * 32]) : 0.0f;
#pragma unroll
      for (int o = 16; o; o >>= 1) {
        x0 += __shfl_down(x0, o, 32);
        x1 += __shfl_down(x1, o, 32);
      }
      if (lane == 0) { shb0s = x0; shb1s = x1; }
    }
    __syncthreads();
    return make_float2(shb0s, shb1s);
  };

  floatx4 y, fy, k2, k3, k4, k5, k6, k7, yn, av;
  const size_t yidx = (size_t)(rg * 16 + rl) * NDT + cb * 64 + (tid >> 4) * 4;
  y = *(const floatx4*)(bufY + yidx);

  // ---- initial step selection (scipy _select_initial_step) ----
  write_basis(y, TCc + TBc * 0.0f);
  rg_barrier();
  fy = gemm();  // f0
  {
    float s0 = 0.f, s1 = 0.f;
#pragma unroll
    for (int r = 0; r < 4; ++r) {
      float sv = ATOLc + RTOLc * fabsf(y[r]);
      float a = y[r] / sv, b = fy[r] / sv;
      s0 += a * a;
      s1 += b * b;
    }
    float2 d01 = grid_reduce(s0, s1, 0, 1, true);
    const float d0 = sqrtf(d01.x / NELF);
    const float d1 = sqrtf(d01.y / NELF);
    const float h0 = (d0 < 1e-5f || d1 < 1e-5f) ? 1e-6f : 0.01f * d0 / d1;
    av = y + h0 * fy;
    write_basis(av, TCc + TBc * h0);
    rg_barrier();
    k2 = gemm();  // f1 (temp)
    float s2 = 0.f;
#pragma unroll
    for (int r = 0; r < 4; ++r) {
      float sv = ATOLc + RTOLc * fabsf(y[r]);
      float dd = (k2[r] - fy[r]) / sv;
      s2 += dd * dd;
    }
    const float d2 = sqrtf(grid_reduce(s2, 0.f, 2, 0, false).x / NELF) / h0;
    const float dmax = fmaxf(d1, d2);
    const float h1i = (dmax <= 1e-15f) ? fmaxf(1e-6f, h0 * 1e-3f) : powf(0.01f / dmax, 0.2f);
    float h = fminf(fminf(100.0f * h0, h1i), 1.0f);
    float t = 0.0f;
    bool done = false;
    int it = 0;

    const float a21 = (float)(1.0 / 5.0);
    const float a31 = (float)(3.0 / 40.0), a32 = (float)(9.0 / 40.0);
    const float a41 = (float)(44.0 / 45.0), a42 = (float)(-56.0 / 15.0), a43 = (float)(32.0 / 9.0);
    const float a51 = (float)(19372.0 / 6561.0), a52 = (float)(-25360.0 / 2187.0),
                a53 = (float)(64448.0 / 6561.0), a54 = (float)(-212.0 / 729.0);
    const float a61 = (float)(9017.0 / 3168.0), a62 = (float)(-355.0 / 33.0),
                a63 = (float)(46732.0 / 5247.0), a64 = (float)(49.0 / 176.0),
                a65 = (float)(-5103.0 / 18656.0);
    const float b1 = (float)(35.0 / 384.0), b3 = (float)(500.0 / 1113.0),
                b4 = (float)(125.0 / 192.0), b5 = (float)(-2187.0 / 6784.0),
                b6 = (float)(11.0 / 84.0);
    const float e1c = (float)(71.0 / 57600.0), e3c = (float)(-71.0 / 16695.0),
                e4c = (float)(71.0 / 1920.0), e5c = (float)(-17253.0 / 339200.0),
                e6c = (float)(22.0 / 525.0), e7c = (float)(-1.0 / 40.0);
    const float c89 = (float)(8.0 / 9.0);

    while (true) {
      const float hs = fminf(h, 1.0f - t);

      av = y + (hs * a21) * fy;
      write_basis(av, TCc + TBc * (t + 0.2f * hs));
      rg_barrier();
      k2 = gemm();

      av = y + hs * (a31 * fy + a32 * k2);
      write_basis(av, TCc + TBc * (t + 0.3f * hs));
      rg_barrier();
      k3 = gemm();

      av = y + hs * (a41 * fy + a42 * k2 + a43 * k3);
      write_basis(av, TCc + TBc * (t + 0.8f * hs));
      rg_barrier();
      k4 = gemm();

      av = y + hs * (a51 * fy + a52 * k2 + a53 * k3 + a54 * k4);
      write_basis(av, TCc + TBc * (t + c89 * hs));
      rg_barrier();
      k5 = gemm();

      av = y + hs * (a61 * fy + a62 * k2 + a63 * k3 + a64 * k4 + a65 * k5);
      write_basis(av, TCc + TBc * (t + hs));
      rg_barrier();
      k6 = gemm();

      yn = y + hs * (b1 * fy + b3 * k3 + b4 * k4 + b5 * k5 + b6 * k6);
      write_basis(yn, TCc + TBc * (t + hs));  // FSAL stage input
      rg_barrier();
      k7 = gemm();

      float es = 0.f;
#pragma unroll
      for (int r = 0; r < 4; ++r) {
        float errc = hs * (e1c * fy[r] + e3c * k3[r] + e4c * k4[r] + e5c * k5[r] + e6c * k6[r] +
                           e7c * k7[r]);
        float sv = ATOLc + RTOLc * fmaxf(fabsf(y[r]), fabsf(yn[r]));
        float dd = errc / sv;
        es += dd * dd;
      }
      const float en = sqrtf(grid_reduce(es, 0.f, 3 + it, 0, false).x / NELF);
      const bool accept = en < 1.0f;
      const float safe = fmaxf(en, 1e-10f);
      float fac = 0.9f * powf(safe, -0.2f);
      fac = accept ? fminf(10.0f, fac) : fmaxf(0.2f, fac);
      if (accept) {
        t = t + hs;
        y = yn;
        fy = k7;
      }
      h = hs * fac;
      done = done || (t >= 1.0f - 1e-7f);
      ++it;
      if (done || it >= 20) break;
    }
  }

  *(floatx4*)(bufY + yidx) = y;  // A_f for the output GEMM
}

extern "C" void kernel_launch(void* const* d_in, const int* in_sizes, int n_in,
                              void* d_out, int out_size, void* d_ws, size_t ws_size,
                              hipStream_t stream) {
  (void)in_sizes; (void)n_in; (void)out_size; (void)ws_size;
  const float* x = (const float*)d_in[0];
  const float* P = (const float*)d_in[1];
  const float* C = (const float*)d_in[2];
  const float* F = (const float*)d_in[3];
  float* out = (float*)d_out;
  float* ws = (float*)d_ws;

  // pack C/P/F -> bf16 frags, zero ctl region (one launch)
  hipLaunchKernelGGL(pack_all, dim3(1024), dim3(256), 0, stream, C, P, F,
                     (__bf16*)(ws + BFC_OFF), (unsigned short*)(ws + BFP_OFF),
                     (unsigned short*)(ws + BFF_OFF), (unsigned*)ws);
  // A0 = x @ P (bf16 MFMA) -> bufY
  hipLaunchKernelGGL(gemm_mf, dim3(256), dim3(256), 0, stream, x, (const __bf16*)(ws + BFP_OFF),
                     ws + BUF_OFF);
  // cooperative RK45 (per-access coherent exchange, no cache-wide fences)
  float* wsf = ws;
  void* kargs[] = {(void*)&wsf};
  hipLaunchCooperativeKernel((void*)ode_mfma, dim3(256), dim3(256), kargs, 0, stream);
  // out = A_f @ F (bf16 MFMA)
  hipLaunchKernelGGL(gemm_mf, dim3(256), dim3(256), 0, stream, ws + BUF_OFF,
                     (const __bf16*)(ws + BFF_OFF), out);
}

// Round 9
// 149.620 us; speedup vs baseline: 8.7123x; 1.2231x over previous
//
#include <hip/hip_runtime.h>
#include <cmath>

typedef float floatx4 __attribute__((ext_vector_type(4)));
typedef __bf16 bf16x8 __attribute__((ext_vector_type(8)));

#define NDT 512
#define NEL (512 * 512)
#define NELF 262144.0f

// ---- ws layout (round-6-proven ctl) ----
// CNT   uint  [0 .. 1024)      per-rg arrival counter at rg*32
// RCNT  uint  [1024 .. 2560)   per-slot release counter at 1024 + sa*32
// PART1 float [4096 .. 16384)  sa*256 + rg*8 + cb
// PART2 float [16384 .. 41088) (sa*32 + rg)*32
// data (float offsets):
#define AF0_OFF 65536
#define AF1_OFF (65536 + 262144)
#define YF_OFF (65536 + 2 * 262144)
#define BFC_OFF (YF_OFF + 131072)
#define BFP_OFF (BFC_OFF + 262144)
#define BFF_OFF (BFP_OFF + 131072)

#define RTOLc 1e-3f
#define ATOLc 1e-6f
#define TAc 1.0f
#define TBc 1.0f
#define TCc 0.0f

union UB { uint4 u; bf16x8 v; };
union UB2 { unsigned long long q[2]; uint4 u; bf16x8 v; };

__device__ __forceinline__ uint32_t f2bf(float f) {
  uint32_t u = __float_as_uint(f);
  return (u + 0x7fffu + ((u >> 16) & 1u)) >> 16;
}

#define AST(p, v) __hip_atomic_store((p), (v), __ATOMIC_RELAXED, __HIP_MEMORY_SCOPE_AGENT)
#define ALD(p) __hip_atomic_load((p), __ATOMIC_RELAXED, __HIP_MEMORY_SCOPE_AGENT)

// ---- pack C->K1024 frags, P/F->K512 frags; block 0 zeroes ctl ----
__global__ __launch_bounds__(256) void pack_all(const float* __restrict__ C,
                                                const float* __restrict__ P,
                                                const float* __restrict__ F,
                                                __bf16* __restrict__ BfC,
                                                unsigned short* __restrict__ BfP,
                                                unsigned short* __restrict__ BfF,
                                                unsigned* __restrict__ ctl) {
  const int bid = blockIdx.x, tid = threadIdx.x;
  if (bid == 0) {
    for (int i = tid; i < 4096; i += 256) ctl[i] = 0u;
  }
  if (bid < 512) {
    int t = bid * 256 + tid;
    int i = t >> 8;
    int pr = t & 255;  // K0 = pr*4
    floatx4 v = *(const floatx4*)(C + (size_t)i * 1024 + pr * 4);
    uint32_t w0 = f2bf(v[0]) | (f2bf(v[1]) << 16);
    uint32_t w1 = f2bf(v[2]) | (f2bf(v[3]) << 16);
    int c0 = i >> 4;
    int kc = pr >> 3;
    int lq = (pr >> 1) & 3;
    int ln = (i & 15) | (lq << 4);
    int jp = (pr & 1) * 4;
    uint2 val; val.x = w0; val.y = w1;
    *(uint2*)(BfC + ((size_t)(c0 * 32 + kc) * 64 + ln) * 8 + jp) = val;
  } else {
    const float* M = (bid < 768) ? P : F;
    unsigned short* Bf = (bid < 768) ? BfP : BfF;
    int t = ((bid < 768) ? (bid - 512) : (bid - 768)) * 256 + tid;
    int idx = t * 4;
    int k = idx >> 9;
    int n0 = idx & 511;
    floatx4 v = *(const floatx4*)(M + (size_t)k * NDT + n0);
    int kc = k >> 5;
    int lq = (k >> 3) & 3;
    int j = k & 7;
#pragma unroll
    for (int i = 0; i < 4; ++i) {
      int n = n0 + i;
      int nf = n >> 4;
      int lane = (n & 15) | (lq << 4);
      Bf[((size_t)(nf * 16 + kc) * 64 + lane) * 8 + j] = (unsigned short)f2bf(v[i]);
    }
  }
}

// ---- fused kernel: A0 GEMM + RK45 + out GEMM ----
// No cooperative-groups API used; co-residency by capacity (256 blocks,
// launch_bounds(256,1), 34 KB LDS => >=2 blocks/CU, grid == CU count).
__global__ __launch_bounds__(256, 1) void ode_mfma(const float* __restrict__ x,
                                                   float* __restrict__ out,
                                                   float* __restrict__ ws) {
  __shared__ __align__(16) float red[4][16][68];
  __shared__ __align__(16) unsigned short ldsX[16 * 64 * 8];  // 16 KiB
  __shared__ float bred[4];
  __shared__ float shb0s, shb1s;

  unsigned* CNT = (unsigned*)ws;                // per-rg counters, stride 32
  unsigned* RCNT = ((unsigned*)ws) + 1024;      // per-slot counters, stride 32
  float* PART1 = ws + 4096;
  float* PART2 = ws + 16384;
  unsigned long long* AfA = (unsigned long long*)(ws + AF0_OFF);
  unsigned long long* AfB = (unsigned long long*)(ws + AF1_OFF);
  unsigned long long* YF = (unsigned long long*)(ws + YF_OFF);
  const __bf16* Bf = (const __bf16*)(ws + BFC_OFF);
  const __bf16* BfP = (const __bf16*)(ws + BFP_OFF);
  const __bf16* BfF = (const __bf16*)(ws + BFF_OFF);

  const int tid = threadIdx.x;
  const int lane = tid & 63;
  const int w = tid >> 6;          // wave id = K-chunk
  const int cb = blockIdx.x >> 5;  // col-slice 64*cb..64*cb+63
  const int rg = blockIdx.x & 31;  // rows 16*rg..16*rg+15
  const int rl = tid & 15;         // owned row
  const int gcq = cb * 16 + (tid >> 4);  // owned global col-quad

  // persistent register-resident C-frags (K=1024): wave w owns kc 8w..8w+7
  UB Breg[4][8];
#pragma unroll
  for (int cf = 0; cf < 4; ++cf)
#pragma unroll
    for (int i = 0; i < 8; ++i)
      Breg[cf][i].u =
          *(const uint4*)(Bf + (((size_t)(cb * 4 + cf) * 32 + 8 * w + i) * 64 + lane) * 8);

  int rg_phase = 0, par = 0;

  auto rg_barrier = [&]() {
    __syncthreads();  // compiler-emitted vmcnt(0) before s_barrier drains stores
    ++rg_phase;
    if (tid == 0) {
      __hip_atomic_fetch_add(&CNT[rg * 32], 1u, __ATOMIC_RELAXED, __HIP_MEMORY_SCOPE_AGENT);
      while (ALD(&CNT[rg * 32]) < 8u * (unsigned)rg_phase) __builtin_amdgcn_s_sleep(1);
    }
    __syncthreads();
  };

  // cross-wave K-reduction of 4 col-frag accumulators -> thread's floatx4 patch
  auto reduce4 = [&](floatx4 a0, floatx4 a1, floatx4 a2, floatx4 a3) -> floatx4 {
    __syncthreads();  // guard red reuse
    const int q = lane >> 4, l4 = lane & 15;
#pragma unroll
    for (int ri = 0; ri < 4; ++ri) {
      red[w][4 * q + ri][l4] = a0[ri];
      red[w][4 * q + ri][16 + l4] = a1[ri];
      red[w][4 * q + ri][32 + l4] = a2[ri];
      red[w][4 * q + ri][48 + l4] = a3[ri];
    }
    __syncthreads();
    const int c0 = (tid >> 4) * 4;
    floatx4 o = *(const floatx4*)&red[0][rl][c0];
    o += *(const floatx4*)&red[1][rl][c0];
    o += *(const floatx4*)&red[2][rl][c0];
    o += *(const floatx4*)&red[3][rl][c0];
    return o;
  };

  // basis write slot (K=1024 frag layout, sin/cos interleaved over K=2*col)
  const int kcw = gcq >> 2;
  const int alw = rl | ((gcq & 3) << 4);
  const size_t wslot = ((size_t)(rg * 32 + kcw) * 64 + alw) * 2;

  auto write_basis = [&](floatx4 av, float targ) {
    uint32_t d[4];
#pragma unroll
    for (int e = 0; e < 4; ++e) {
      float s, c;
      __sincosf(TAc * av[e] + targ, &s, &c);
      d[e] = f2bf(s) | (f2bf(c) << 16);
    }
    unsigned long long* Ap = (par ? AfB : AfA) + wslot;
    AST(Ap, (unsigned long long)d[0] | ((unsigned long long)d[1] << 32));
    AST(Ap + 1, (unsigned long long)d[2] | ((unsigned long long)d[3] << 32));
  };

  auto gemm = [&]() -> floatx4 {
    const unsigned long long* Ap =
        (par ? AfB : AfA) + ((size_t)(rg * 32 + 8 * w) * 64 + lane) * 2;
    UB2 a[8];
#pragma unroll
    for (int i = 0; i < 8; ++i) {
      a[i].q[0] = ALD(Ap + (size_t)i * 128);
      a[i].q[1] = ALD(Ap + (size_t)i * 128 + 1);
    }
    floatx4 acc0 = {0.f, 0.f, 0.f, 0.f}, acc1 = acc0, acc2 = acc0, acc3 = acc0;
#pragma unroll
    for (int i = 0; i < 8; ++i) {
      acc0 = __builtin_amdgcn_mfma_f32_16x16x32_bf16(a[i].v, Breg[0][i].v, acc0, 0, 0, 0);
      acc1 = __builtin_amdgcn_mfma_f32_16x16x32_bf16(a[i].v, Breg[1][i].v, acc1, 0, 0, 0);
      acc2 = __builtin_amdgcn_mfma_f32_16x16x32_bf16(a[i].v, Breg[2][i].v, acc2, 0, 0, 0);
      acc3 = __builtin_amdgcn_mfma_f32_16x16x32_bf16(a[i].v, Breg[3][i].v, acc3, 0, 0, 0);
    }
    par ^= 1;
    return reduce4(acc0, acc1, acc2, acc3);
  };

  auto block_sum = [&](float v) -> float {
#pragma unroll
    for (int o = 32; o; o >>= 1) v += __shfl_down(v, o, 64);
    __syncthreads();
    if (lane == 0) bred[w] = v;
    __syncthreads();
    return (tid == 0) ? (bred[0] + bred[1] + bred[2] + bred[3]) : 0.0f;
  };

  // deterministic 2-level grid reduce (round-6 verbatim)
  auto grid_reduce = [&](float va, float vb, int sa, int sb, bool two) -> float2 {
    float ba = block_sum(va);
    float bb = two ? block_sum(vb) : 0.0f;
    ++rg_phase;
    if (tid == 0) {
      AST(&PART1[sa * 256 + rg * 8 + cb], ba);
      if (two) AST(&PART1[sb * 256 + rg * 8 + cb], bb);
      asm volatile("s_waitcnt vmcnt(0)" ::: "memory");
      __hip_atomic_fetch_add(&CNT[rg * 32], 1u, __ATOMIC_RELAXED, __HIP_MEMORY_SCOPE_AGENT);
    }
    if (cb == 0 && tid == 0) {
      while (ALD(&CNT[rg * 32]) < 8u * (unsigned)rg_phase) __builtin_amdgcn_s_sleep(1);
      float ra = 0.f, rb = 0.f;
#pragma unroll
      for (int i = 0; i < 8; ++i) ra += ALD(&PART1[sa * 256 + rg * 8 + i]);
      AST(&PART2[(size_t)(sa * 32 + rg) * 32], ra);
      if (two) {
#pragma unroll
        for (int i = 0; i < 8; ++i) rb += ALD(&PART1[sb * 256 + rg * 8 + i]);
        AST(&PART2[(size_t)(sb * 32 + rg) * 32], rb);
      }
      asm volatile("s_waitcnt vmcnt(0)" ::: "memory");
      __hip_atomic_fetch_add(&RCNT[sa * 32], 1u, __ATOMIC_RELAXED, __HIP_MEMORY_SCOPE_AGENT);
    }
    if (tid == 0) {
      while (ALD(&RCNT[sa * 32]) < 32u) __builtin_amdgcn_s_sleep(1);
    }
    __syncthreads();
    if (w == 0) {
      float x0 = (lane < 32) ? ALD(&PART2[(size_t)(sa * 32 + lane) * 32]) : 0.0f;
      float x1 = (two && lane < 32) ? ALD(&PART2[(size_t)(sb * 32 + lane) * 32]) : 0.0f;
#pragma unroll
      for (int o = 16; o; o >>= 1) {
        x0 += __shfl_down(x0, o, 32);
        x1 += __shfl_down(x1, o, 32);
      }
      if (lane == 0) { shb0s = x0; shb1s = x1; }
    }
    __syncthreads();
    return make_float2(shb0s, shb1s);
  };

  // ---- phase A0: y = (x @ P) patch, K=512 MFMA vs P-frags ----
  floatx4 y, fy, k2, k3, k4, k5, k6, k7, yn, av;
  {
    for (int idx = tid; idx < 8192; idx += 256) {
      int r = idx >> 9, k = idx & 511;
      float v = x[(size_t)(rg * 16 + r) * NDT + k];
      int al = r | (((k >> 3) & 3) << 4);
      ldsX[((size_t)(k >> 5) * 64 + al) * 8 + (k & 7)] = (unsigned short)f2bf(v);
    }
    __syncthreads();
    floatx4 a0 = {0.f, 0.f, 0.f, 0.f}, a1 = a0, a2 = a0, a3 = a0;
#pragma unroll
    for (int i = 0; i < 4; ++i) {
      UB a, b;
      a.u = *(const uint4*)(ldsX + ((size_t)(4 * w + i) * 64 + lane) * 8);
      b.u = *(const uint4*)(BfP + (((size_t)(cb * 4 + 0) * 16 + 4 * w + i) * 64 + lane) * 8);
      a0 = __builtin_amdgcn_mfma_f32_16x16x32_bf16(a.v, b.v, a0, 0, 0, 0);
      b.u = *(const uint4*)(BfP + (((size_t)(cb * 4 + 1) * 16 + 4 * w + i) * 64 + lane) * 8);
      a1 = __builtin_amdgcn_mfma_f32_16x16x32_bf16(a.v, b.v, a1, 0, 0, 0);
      b.u = *(const uint4*)(BfP + (((size_t)(cb * 4 + 2) * 16 + 4 * w + i) * 64 + lane) * 8);
      a2 = __builtin_amdgcn_mfma_f32_16x16x32_bf16(a.v, b.v, a2, 0, 0, 0);
      b.u = *(const uint4*)(BfP + (((size_t)(cb * 4 + 3) * 16 + 4 * w + i) * 64 + lane) * 8);
      a3 = __builtin_amdgcn_mfma_f32_16x16x32_bf16(a.v, b.v, a3, 0, 0, 0);
    }
    y = reduce4(a0, a1, a2, a3);
  }

  // ---- initial step selection (scipy _select_initial_step) ----
  write_basis(y, TCc + TBc * 0.0f);
  rg_barrier();
  fy = gemm();  // f0
  {
    float s0 = 0.f, s1 = 0.f;
#pragma unroll
    for (int r = 0; r < 4; ++r) {
      float sv = ATOLc + RTOLc * fabsf(y[r]);
      float a = y[r] / sv, b = fy[r] / sv;
      s0 += a * a;
      s1 += b * b;
    }
    float2 d01 = grid_reduce(s0, s1, 0, 1, true);
    const float d0 = sqrtf(d01.x / NELF);
    const float d1 = sqrtf(d01.y / NELF);
    const float h0 = (d0 < 1e-5f || d1 < 1e-5f) ? 1e-6f : 0.01f * d0 / d1;
    av = y + h0 * fy;
    write_basis(av, TCc + TBc * h0);
    rg_barrier();
    k2 = gemm();  // f1 (temp)
    float s2 = 0.f;
#pragma unroll
    for (int r = 0; r < 4; ++r) {
      float sv = ATOLc + RTOLc * fabsf(y[r]);
      float dd = (k2[r] - fy[r]) / sv;
      s2 += dd * dd;
    }
    const float d2 = sqrtf(grid_reduce(s2, 0.f, 2, 0, false).x / NELF) / h0;
    const float dmax = fmaxf(d1, d2);
    const float h1i = (dmax <= 1e-15f) ? fmaxf(1e-6f, h0 * 1e-3f) : powf(0.01f / dmax, 0.2f);
    float h = fminf(fminf(100.0f * h0, h1i), 1.0f);
    float t = 0.0f;
    bool done = false;
    int it = 0;

    const float a21 = (float)(1.0 / 5.0);
    const float a31 = (float)(3.0 / 40.0), a32 = (float)(9.0 / 40.0);
    const float a41 = (float)(44.0 / 45.0), a42 = (float)(-56.0 / 15.0), a43 = (float)(32.0 / 9.0);
    const float a51 = (float)(19372.0 / 6561.0), a52 = (float)(-25360.0 / 2187.0),
                a53 = (float)(64448.0 / 6561.0), a54 = (float)(-212.0 / 729.0);
    const float a61 = (float)(9017.0 / 3168.0), a62 = (float)(-355.0 / 33.0),
                a63 = (float)(46732.0 / 5247.0), a64 = (float)(49.0 / 176.0),
                a65 = (float)(-5103.0 / 18656.0);
    const float b1 = (float)(35.0 / 384.0), b3 = (float)(500.0 / 1113.0),
                b4 = (float)(125.0 / 192.0), b5 = (float)(-2187.0 / 6784.0),
                b6 = (float)(11.0 / 84.0);
    const float e1c = (float)(71.0 / 57600.0), e3c = (float)(-71.0 / 16695.0),
                e4c = (float)(71.0 / 1920.0), e5c = (float)(-17253.0 / 339200.0),
                e6c = (float)(22.0 / 525.0), e7c = (float)(-1.0 / 40.0);
    const float c89 = (float)(8.0 / 9.0);

    while (true) {
      const float hs = fminf(h, 1.0f - t);

      av = y + (hs * a21) * fy;
      write_basis(av, TCc + TBc * (t + 0.2f * hs));
      rg_barrier();
      k2 = gemm();

      av = y + hs * (a31 * fy + a32 * k2);
      write_basis(av, TCc + TBc * (t + 0.3f * hs));
      rg_barrier();
      k3 = gemm();

      av = y + hs * (a41 * fy + a42 * k2 + a43 * k3);
      write_basis(av, TCc + TBc * (t + 0.8f * hs));
      rg_barrier();
      k4 = gemm();

      av = y + hs * (a51 * fy + a52 * k2 + a53 * k3 + a54 * k4);
      write_basis(av, TCc + TBc * (t + c89 * hs));
      rg_barrier();
      k5 = gemm();

      av = y + hs * (a61 * fy + a62 * k2 + a63 * k3 + a64 * k4 + a65 * k5);
      write_basis(av, TCc + TBc * (t + hs));
      rg_barrier();
      k6 = gemm();

      yn = y + hs * (b1 * fy + b3 * k3 + b4 * k4 + b5 * k5 + b6 * k6);
      write_basis(yn, TCc + TBc * (t + hs));  // FSAL stage input
      rg_barrier();
      k7 = gemm();

      float es = 0.f;
#pragma unroll
      for (int r = 0; r < 4; ++r) {
        float errc = hs * (e1c * fy[r] + e3c * k3[r] + e4c * k4[r] + e5c * k5[r] + e6c * k6[r] +
                           e7c * k7[r]);
        float sv = ATOLc + RTOLc * fmaxf(fabsf(y[r]), fabsf(yn[r]));
        float dd = errc / sv;
        es += dd * dd;
      }
      const float en = sqrtf(grid_reduce(es, 0.f, 3 + it, 0, false).x / NELF);
      const bool accept = en < 1.0f;
      const float safe = fmaxf(en, 1e-10f);
      float fac = 0.9f * powf(safe, -0.2f);
      fac = accept ? fminf(10.0f, fac) : fmaxf(0.2f, fac);
      if (accept) {
        t = t + hs;
        y = yn;
        fy = k7;
      }
      h = hs * fac;
      done = done || (t >= 1.0f - 1e-7f);
      ++it;
      if (done || it >= 20) break;
    }
  }

  // ---- final phase: out = A_f @ F (exchange y as K=512 frags, MFMA vs F-frags) ----
  {
    uint32_t d0 = f2bf(y[0]) | (f2bf(y[1]) << 16);
    uint32_t d1 = f2bf(y[2]) | (f2bf(y[3]) << 16);
    const int kcF = gcq >> 3;
    const int alF = rl | (((gcq >> 1) & 3) << 4);
    AST(YF + ((size_t)(rg * 16 + kcF) * 64 + alF) * 2 + (gcq & 1),
        (unsigned long long)d0 | ((unsigned long long)d1 << 32));
  }
  rg_barrier();
  {
    floatx4 a0 = {0.f, 0.f, 0.f, 0.f}, a1 = a0, a2 = a0, a3 = a0;
#pragma unroll
    for (int i = 0; i < 4; ++i) {
      UB2 a;
      const size_t base = ((size_t)(rg * 16 + 4 * w + i) * 64 + lane) * 2;
      a.q[0] = ALD(YF + base);
      a.q[1] = ALD(YF + base + 1);
      UB b;
      b.u = *(const uint4*)(BfF + (((size_t)(cb * 4 + 0) * 16 + 4 * w + i) * 64 + lane) * 8);
      a0 = __builtin_amdgcn_mfma_f32_16x16x32_bf16(a.v, b.v, a0, 0, 0, 0);
      b.u = *(const uint4*)(BfF + (((size_t)(cb * 4 + 1) * 16 + 4 * w + i) * 64 + lane) * 8);
      a1 = __builtin_amdgcn_mfma_f32_16x16x32_bf16(a.v, b.v, a1, 0, 0, 0);
      b.u = *(const uint4*)(BfF + (((size_t)(cb * 4 + 2) * 16 + 4 * w + i) * 64 + lane) * 8);
      a2 = __builtin_amdgcn_mfma_f32_16x16x32_bf16(a.v, b.v, a2, 0, 0, 0);
      b.u = *(const uint4*)(BfF + (((size_t)(cb * 4 + 3) * 16 + 4 * w + i) * 64 + lane) * 8);
      a3 = __builtin_amdgcn_mfma_f32_16x16x32_bf16(a.v, b.v, a3, 0, 0, 0);
    }
    floatx4 o = reduce4(a0, a1, a2, a3);
    *(floatx4*)(out + (size_t)(rg * 16 + rl) * NDT + cb * 64 + (tid >> 4) * 4) = o;
  }
}

extern "C" void kernel_launch(void* const* d_in, const int* in_sizes, int n_in,
                              void* d_out, int out_size, void* d_ws, size_t ws_size,
                              hipStream_t stream) {
  (void)in_sizes; (void)n_in; (void)out_size; (void)ws_size;
  const float* x = (const float*)d_in[0];
  const float* P = (const float*)d_in[1];
  const float* C = (const float*)d_in[2];
  const float* F = (const float*)d_in[3];
  float* out = (float*)d_out;
  float* ws = (float*)d_ws;

  // pack C/P/F -> bf16 frags, zero ctl region
  hipLaunchKernelGGL(pack_all, dim3(1024), dim3(256), 0, stream, C, P, F,
                     (__bf16*)(ws + BFC_OFF), (unsigned short*)(ws + BFP_OFF),
                     (unsigned short*)(ws + BFF_OFF), (unsigned*)ws);
  // fused kernel: A0 + RK45 + out. Plain launch — no cg API used; co-residency
  // guaranteed by capacity (grid=256=CU count, >=2 blocks/CU resources).
  hipLaunchKernelGGL(ode_mfma, dim3(256), dim3(256), 0, stream, x, out, ws);
}